// Round 1
// baseline (311.776 us; speedup 1.0000x reference)
//
#include <hip/hip_runtime.h>

#define B_  8
#define N_  100
#define T_  16
#define TP_ 15     // T-1 output steps (pred_steps == 1)
#define D_  4
#define H_  64
#define E_  9900   // N*(N-1)

// One block (64 threads = 1 wave) per (b, t, receiver n).
// lane = incoming-edge slot; two batches cover the 99 incoming edges.
__global__ __launch_bounds__(64)
void nri_dec(const float* __restrict__ x,        // (B,N,T,D)
             const float* __restrict__ rel_type, // (B,E,K=2)
             const float* __restrict__ w1, const float* __restrict__ b1,   // k=1 slices: (64,8),(64)
             const float* __restrict__ w2, const float* __restrict__ b2,   // (64,64),(64)
             const float* __restrict__ f1w, const float* __restrict__ f1b, // (64,68),(64)
             const float* __restrict__ f2w, const float* __restrict__ f2b, // (64,64),(64)
             const float* __restrict__ f3w, const float* __restrict__ f3b, // (4,64),(4)
             float* __restrict__ out)            // (B,N,TP,D)
{
    const int lane = threadIdx.x;
    const int bid  = blockIdx.x;
    const int n = bid % N_;
    const int t = (bid / N_) % TP_;
    const int b = bid / (N_ * TP_);

    // receiver features (wave-uniform)
    const float4 xr = *reinterpret_cast<const float4*>(
        x + (((size_t)b * N_ + n) * T_ + t) * D_);

    float aggv = 0.f;   // lane g accumulates agg[g]

    #pragma unroll 1
    for (int batch = 0; batch < 2; ++batch) {
        const int  p   = batch * 64 + lane;     // edge position 0..98 valid
        const bool act = (p < N_ - 1);
        const int  pc  = act ? p : 0;
        const int  i   = pc + (pc >= n ? 1 : 0);            // sender
        const int  e   = i * (N_ - 1) + (n < i ? n : n - 1); // global edge id
        const float rt = act ? rel_type[((size_t)b * E_ + e) * 2 + 1] : 0.f;
        const float4 xs = *reinterpret_cast<const float4*>(
            x + (((size_t)b * N_ + i) * T_ + t) * D_);

        // h1 = relu(W1 @ [send, recv] + b1), fully in registers (static idx)
        float h1r[H_];
        #pragma unroll
        for (int h = 0; h < H_; ++h) {
            float a = b1[h];
            a = fmaf(w1[h * 8 + 0], xs.x, a);
            a = fmaf(w1[h * 8 + 1], xs.y, a);
            a = fmaf(w1[h * 8 + 2], xs.z, a);
            a = fmaf(w1[h * 8 + 3], xs.w, a);
            a = fmaf(w1[h * 8 + 4], xr.x, a);
            a = fmaf(w1[h * 8 + 5], xr.y, a);
            a = fmaf(w1[h * 8 + 6], xr.z, a);
            a = fmaf(w1[h * 8 + 7], xr.w, a);
            h1r[h] = fmaxf(a, 0.f);
        }

        // h2[g] = relu(W2[g,:] @ h1 + b2[g]); msg = h2 * rt; reduce over lanes
        #pragma unroll 1
        for (int g = 0; g < H_; ++g) {
            float a = b2[g];                    // uniform -> s_load
            #pragma unroll
            for (int h = 0; h < H_; ++h)
                a = fmaf(w2[g * H_ + h], h1r[h], a);   // uniform weights -> SGPR operand
            float m = fmaxf(a, 0.f) * rt;       // rt==0 masks inactive lanes
            #pragma unroll
            for (int s = 1; s < 64; s <<= 1)
                m += __shfl_xor(m, s, 64);      // butterfly sum over 64 lanes
            aggv += (lane == g) ? m : 0.f;
        }
    }

    // ---- output MLP: [x_n, agg] (68) -> 64 -> 64 -> 4, residual ----
    __shared__ float s_agg[H_];
    __shared__ float s_p1[H_];
    __shared__ float s_p2[H_];

    s_agg[lane] = aggv;
    __syncthreads();

    {   // p1 = relu(fc1 @ [x, agg] + b)
        float a = f1b[lane];
        const float* wr = f1w + lane * (D_ + H_);
        a = fmaf(wr[0], xr.x, a);
        a = fmaf(wr[1], xr.y, a);
        a = fmaf(wr[2], xr.z, a);
        a = fmaf(wr[3], xr.w, a);
        #pragma unroll
        for (int f = 0; f < H_; ++f)
            a = fmaf(wr[4 + f], s_agg[f], a);
        s_p1[lane] = fmaxf(a, 0.f);
    }
    __syncthreads();

    {   // p2 = relu(fc2 @ p1 + b)
        float a = f2b[lane];
        const float* wr = f2w + lane * H_;
        #pragma unroll
        for (int h = 0; h < H_; ++h)
            a = fmaf(wr[h], s_p1[h], a);
        s_p2[lane] = fmaxf(a, 0.f);
    }
    __syncthreads();

    if (lane < D_) {   // p3 = fc3 @ p2 + b; out = x + p3
        float a = f3b[lane];
        const float* wr = f3w + lane * H_;
        #pragma unroll
        for (int h = 0; h < H_; ++h)
            a = fmaf(wr[h], s_p2[h], a);
        const float xv = (lane == 0) ? xr.x : (lane == 1) ? xr.y
                       : (lane == 2) ? xr.z : xr.w;
        out[(((size_t)b * N_ + n) * TP_ + t) * D_ + lane] = xv + a;
    }
}

extern "C" void kernel_launch(void* const* d_in, const int* in_sizes, int n_in,
                              void* d_out, int out_size, void* d_ws, size_t ws_size,
                              hipStream_t stream) {
    const float* x   = (const float*)d_in[0];
    const float* rt  = (const float*)d_in[1];
    // d_in[2]=rel_rec, d_in[3]=rel_send: one-hot, replaced by index math
    const float* w1  = (const float*)d_in[4] + 1 * H_ * 2 * D_;  // k=1 slice
    const float* b1  = (const float*)d_in[5] + 1 * H_;
    const float* w2  = (const float*)d_in[6] + 1 * H_ * H_;
    const float* b2  = (const float*)d_in[7] + 1 * H_;
    const float* f1w = (const float*)d_in[8];
    const float* f1b = (const float*)d_in[9];
    const float* f2w = (const float*)d_in[10];
    const float* f2b = (const float*)d_in[11];
    const float* f3w = (const float*)d_in[12];
    const float* f3b = (const float*)d_in[13];
    // d_in[14] = pred_steps (always 1 for this problem's shapes)
    float* out = (float*)d_out;

    dim3 grid(B_ * TP_ * N_);
    nri_dec<<<grid, 64, 0, stream>>>(x, rt, w1, b1, w2, b2,
                                     f1w, f1b, f2w, f2b, f3w, f3b, out);
}

// Round 2
// 192.362 us; speedup vs baseline: 1.6208x; 1.6208x over previous
//
#include <hip/hip_runtime.h>

#define B_  8
#define N_  100
#define T_  16
#define TP_ 15     // T-1 output steps (pred_steps == 1)
#define D_  4
#define H_  64
#define E_  9900   // N*(N-1)
#define UPAD 68    // u_lds row stride (floats): 2-way bank alias only

typedef __attribute__((ext_vector_type(8))) short bf16x8;
typedef __attribute__((ext_vector_type(4))) float f32x4;

__device__ __forceinline__ short f2bf(float f) {
    union { float f; unsigned u; } v; v.f = f;
    unsigned r = v.u + 0x7fffu + ((v.u >> 16) & 1u);   // round-nearest-even
    return (short)(r >> 16);
}

__device__ __forceinline__ bf16x8 pack8(float4 a, float4 b) {
    bf16x8 r;
    r[0] = f2bf(a.x); r[1] = f2bf(a.y); r[2] = f2bf(a.z); r[3] = f2bf(a.w);
    r[4] = f2bf(b.x); r[5] = f2bf(b.y); r[6] = f2bf(b.z); r[7] = f2bf(b.w);
    return r;
}

__device__ __forceinline__ bf16x8 pack8_relu_add(float4 u0, float4 u1,
                                                 float4 v0, float4 v1) {
    bf16x8 r;
    r[0] = f2bf(fmaxf(u0.x + v0.x, 0.f)); r[1] = f2bf(fmaxf(u0.y + v0.y, 0.f));
    r[2] = f2bf(fmaxf(u0.z + v0.z, 0.f)); r[3] = f2bf(fmaxf(u0.w + v0.w, 0.f));
    r[4] = f2bf(fmaxf(u1.x + v1.x, 0.f)); r[5] = f2bf(fmaxf(u1.y + v1.y, 0.f));
    r[6] = f2bf(fmaxf(u1.z + v1.z, 0.f)); r[7] = f2bf(fmaxf(u1.w + v1.w, 0.f));
    return r;
}

// One block (256 thr = 4 waves) per (b, t, receiver n).
// Wave w owns edge rows 32w..32w+31 of the padded 128-row edge tile.
__global__ __launch_bounds__(256)
void nri_mfma(const float* __restrict__ x,        // (B,N,T,D)
              const float* __restrict__ rel,      // (B,E,2)
              const float* __restrict__ w1, const float* __restrict__ b1,   // k=1: (64,8),(64)
              const float* __restrict__ w2, const float* __restrict__ b2,   // k=1: (64,64),(64)
              const float* __restrict__ f1w, const float* __restrict__ f1b, // (64,68),(64)
              const float* __restrict__ f2w, const float* __restrict__ f2b, // (64,64),(64)
              const float* __restrict__ f3w, const float* __restrict__ f3b, // (4,64),(4)
              float* __restrict__ out)            // (B,N,TP,D)
{
    __shared__ float u_lds[N_][UPAD];  // sender-side h1 pre-activations
    __shared__ float v_lds[H_];        // receiver-side + b1
    __shared__ float rt_lds[128];      // rel_type[:,:,1] per edge row (0 pad)
    __shared__ float agg_part[4][H_];
    __shared__ float s_agg[H_], s_p1[H_], s_p2[H_];

    const int tid  = threadIdx.x;
    const int lane = tid & 63;
    const int w    = tid >> 6;
    const int bid  = blockIdx.x;
    const int n = bid % N_;
    const int t = (bid / N_) % TP_;
    const int b = bid / (N_ * TP_);

    // ---- phase A: u[i][h] for all 100 nodes; v[h] for receiver n ----
    const float4 ws4 = *reinterpret_cast<const float4*>(w1 + lane * 8);
    const float4 wr4 = *reinterpret_cast<const float4*>(w1 + lane * 8 + 4);
    #pragma unroll
    for (int it = 0; it < 25; ++it) {
        const int r = it * 4 + w;
        const float4 xv = *reinterpret_cast<const float4*>(
            x + (((size_t)b * N_ + r) * T_ + t) * D_);
        u_lds[r][lane] = ws4.x * xv.x + ws4.y * xv.y + ws4.z * xv.z + ws4.w * xv.w;
    }
    const float4 xr = *reinterpret_cast<const float4*>(
        x + (((size_t)b * N_ + n) * T_ + t) * D_);
    if (w == 0)
        v_lds[lane] = wr4.x * xr.x + wr4.y * xr.y + wr4.z * xr.z + wr4.w * xr.w
                      + b1[lane];
    if (tid < 128) {
        float rt = 0.f;
        if (tid < N_ - 1) {
            const int i = tid + (tid >= n ? 1 : 0);
            const int eid = i * (N_ - 1) + (n < i ? n : n - 1);
            rt = rel[((size_t)b * E_ + eid) * 2 + 1];
        }
        rt_lds[tid] = rt;
    }
    __syncthreads();

    // ---- phase B: h2 = relu(h1 @ W2^T + b2) via MFMA, 128x64, K=64 ----
    const int col = lane & 15;          // output col g (low), A row (low)
    const int kq  = (lane >> 4) * 8;    // k sub-chunk within 32
    int e0 = 32 * w + col;              // A row, m=0
    int e1 = e0 + 16;                   // A row, m=1
    int i0 = e0 + (e0 >= n ? 1 : 0); if (i0 > N_ - 1) i0 = N_ - 1;
    int i1 = e1 + (e1 >= n ? 1 : 0); if (i1 > N_ - 1) i1 = N_ - 1;

    f32x4 acc[2][4] = {};
    #pragma unroll
    for (int s = 0; s < 2; ++s) {
        const int kk = s * 32 + kq;
        // B fragments: B[k][g] = w2[g][k]
        bf16x8 bf[4];
        #pragma unroll
        for (int nt = 0; nt < 4; ++nt) {
            const float* wp = w2 + (nt * 16 + col) * H_ + kk;
            bf[nt] = pack8(*reinterpret_cast<const float4*>(wp),
                           *reinterpret_cast<const float4*>(wp + 4));
        }
        // A fragments: h1[e][k] = relu(u[i][k] + v[k])
        const float4 v0 = *reinterpret_cast<const float4*>(&v_lds[kk]);
        const float4 v1 = *reinterpret_cast<const float4*>(&v_lds[kk + 4]);
        bf16x8 af[2];
        {
            const float* up = &u_lds[i0][kk];
            af[0] = pack8_relu_add(*reinterpret_cast<const float4*>(up),
                                   *reinterpret_cast<const float4*>(up + 4), v0, v1);
        }
        {
            const float* up = &u_lds[i1][kk];
            af[1] = pack8_relu_add(*reinterpret_cast<const float4*>(up),
                                   *reinterpret_cast<const float4*>(up + 4), v0, v1);
        }
        #pragma unroll
        for (int m = 0; m < 2; ++m)
            #pragma unroll
            for (int nt = 0; nt < 4; ++nt)
                acc[m][nt] = __builtin_amdgcn_mfma_f32_16x16x32_bf16(
                    af[m], bf[nt], acc[m][nt], 0, 0, 0);
    }

    // ---- aggregation: agg[g] = sum_e rt_e * relu(h2[e][g] + b2[g]) ----
    const int rbase = 32 * w + ((lane >> 4) << 2);  // D row = rbase + 16m + r
    float rt0[4], rt1[4];
    #pragma unroll
    for (int r = 0; r < 4; ++r) {
        rt0[r] = rt_lds[rbase + r];
        rt1[r] = rt_lds[rbase + 16 + r];
    }
    #pragma unroll
    for (int nt = 0; nt < 4; ++nt) {
        const float bb = b2[nt * 16 + col];
        float p = 0.f;
        #pragma unroll
        for (int r = 0; r < 4; ++r) {
            p += fmaxf(acc[0][nt][r] + bb, 0.f) * rt0[r];
            p += fmaxf(acc[1][nt][r] + bb, 0.f) * rt1[r];
        }
        p += __shfl_xor(p, 16, 64);
        p += __shfl_xor(p, 32, 64);
        if ((lane >> 4) == 0) agg_part[w][nt * 16 + col] = p;
    }
    __syncthreads();

    // ---- output MLP on wave 0 only (wave-synchronous; no more barriers) --
    if (w != 0) return;
    s_agg[lane] = agg_part[0][lane] + agg_part[1][lane]
                + agg_part[2][lane] + agg_part[3][lane];
    __builtin_amdgcn_wave_barrier();
    {
        float a = f1b[lane];
        const float* wr = f1w + lane * (D_ + H_);
        a = fmaf(wr[0], xr.x, a);
        a = fmaf(wr[1], xr.y, a);
        a = fmaf(wr[2], xr.z, a);
        a = fmaf(wr[3], xr.w, a);
        #pragma unroll
        for (int f = 0; f < H_; ++f)
            a = fmaf(wr[4 + f], s_agg[f], a);
        s_p1[lane] = fmaxf(a, 0.f);
    }
    __builtin_amdgcn_wave_barrier();
    {
        float a = f2b[lane];
        const float* wr = f2w + lane * H_;
        #pragma unroll
        for (int h = 0; h < H_; ++h)
            a = fmaf(wr[h], s_p1[h], a);
        s_p2[lane] = fmaxf(a, 0.f);
    }
    __builtin_amdgcn_wave_barrier();
    if (lane < D_) {
        float a = f3b[lane];
        const float* wr = f3w + lane * H_;
        #pragma unroll
        for (int h = 0; h < H_; ++h)
            a = fmaf(wr[h], s_p2[h], a);
        const float xv = (lane == 0) ? xr.x : (lane == 1) ? xr.y
                       : (lane == 2) ? xr.z : xr.w;
        out[(((size_t)b * N_ + n) * TP_ + t) * D_ + lane] = xv + a;
    }
}

extern "C" void kernel_launch(void* const* d_in, const int* in_sizes, int n_in,
                              void* d_out, int out_size, void* d_ws, size_t ws_size,
                              hipStream_t stream) {
    const float* x   = (const float*)d_in[0];
    const float* rt  = (const float*)d_in[1];
    // d_in[2]=rel_rec, d_in[3]=rel_send: one-hot -> index arithmetic
    const float* w1  = (const float*)d_in[4] + 1 * H_ * 2 * D_;  // k=1 slice
    const float* b1  = (const float*)d_in[5] + 1 * H_;
    const float* w2  = (const float*)d_in[6] + 1 * H_ * H_;
    const float* b2  = (const float*)d_in[7] + 1 * H_;
    const float* f1w = (const float*)d_in[8];
    const float* f1b = (const float*)d_in[9];
    const float* f2w = (const float*)d_in[10];
    const float* f2b = (const float*)d_in[11];
    const float* f3w = (const float*)d_in[12];
    const float* f3b = (const float*)d_in[13];
    float* out = (float*)d_out;

    dim3 grid(B_ * TP_ * N_);
    nri_mfma<<<grid, 256, 0, stream>>>(x, rt, w1, b1, w2, b2,
                                       f1w, f1b, f2w, f2b, f3w, f3b, out);
}

// Round 3
// 103.363 us; speedup vs baseline: 3.0163x; 1.8610x over previous
//
#include <hip/hip_runtime.h>
#include <hip/hip_bf16.h>

#define B_  8
#define N_  100
#define T_  16
#define TP_ 15     // T-1 output steps (pred_steps == 1)
#define D_  4
#define H_  64
#define E_  9900   // N*(N-1)
#define UPAD 68    // u_lds row stride: +4 banks/row -> 2-way b128 alias (free)
#define RPB 8      // receivers per block
#define NG  13     // ceil(N/RPB) receiver groups

typedef __attribute__((ext_vector_type(8))) short bf16x8;
typedef __attribute__((ext_vector_type(4))) float f32x4;

__device__ __forceinline__ short f2bf(float f) {
    // compiler fuses pairs into v_cvt_pk_bf16_f32 (RNE) on gfx950
    return (short)__builtin_bit_cast(unsigned short, __float2bfloat16(f));
}

__device__ __forceinline__ bf16x8 pack8(float4 a, float4 b) {
    bf16x8 r;
    r[0] = f2bf(a.x); r[1] = f2bf(a.y); r[2] = f2bf(a.z); r[3] = f2bf(a.w);
    r[4] = f2bf(b.x); r[5] = f2bf(b.y); r[6] = f2bf(b.z); r[7] = f2bf(b.w);
    return r;
}

__device__ __forceinline__ bf16x8 pack8_relu_add(float4 u0, float4 u1,
                                                 float4 v0, float4 v1) {
    bf16x8 r;
    r[0] = f2bf(fmaxf(u0.x + v0.x, 0.f)); r[1] = f2bf(fmaxf(u0.y + v0.y, 0.f));
    r[2] = f2bf(fmaxf(u0.z + v0.z, 0.f)); r[3] = f2bf(fmaxf(u0.w + v0.w, 0.f));
    r[4] = f2bf(fmaxf(u1.x + v1.x, 0.f)); r[5] = f2bf(fmaxf(u1.y + v1.y, 0.f));
    r[6] = f2bf(fmaxf(u1.z + v1.z, 0.f)); r[7] = f2bf(fmaxf(u1.w + v1.w, 0.f));
    return r;
}

// One block (4 waves) per (b, t, receiver-group). u staged once per block;
// each wave independently processes one receiver per round (7 m-frag MFMA
// tile, M=112 >= 99 edges), wave-synchronous epilogue. One __syncthreads.
__global__ __launch_bounds__(256)
void nri_v3(const float* __restrict__ x,        // (B,N,T,D)
            const float* __restrict__ rel,      // (B,E,2)
            const float* __restrict__ w1, const float* __restrict__ b1,   // k=1: (64,8),(64)
            const float* __restrict__ w2, const float* __restrict__ b2,   // k=1: (64,64),(64)
            const float* __restrict__ f1w, const float* __restrict__ f1b, // (64,68),(64)
            const float* __restrict__ f2w, const float* __restrict__ f2b, // (64,64),(64)
            const float* __restrict__ f3w, const float* __restrict__ f3b, // (4,64),(4)
            float* __restrict__ out)            // (B,N,TP,D)
{
    __shared__ float u_lds[N_][UPAD];   // sender-side W1send @ x_i
    __shared__ float rt_w[4][112];      // per-wave rel_type (rows 99..111 = 0)
    __shared__ float v_w[4][H_];        // per-wave receiver-side + b1
    __shared__ float agg_w[4][H_];
    __shared__ float p1_w[4][H_];
    __shared__ float p2_w[4][H_];

    const int tid  = threadIdx.x;
    const int lane = tid & 63;
    const int w    = tid >> 6;
    const int bid  = blockIdx.x;
    const int g = bid % NG;
    const int t = (bid / NG) % TP_;
    const int b = bid / (NG * TP_);

    // per-lane W1 row halves (send / recv)
    const float4 ws4 = *reinterpret_cast<const float4*>(w1 + lane * 8);
    const float4 wr4 = *reinterpret_cast<const float4*>(w1 + lane * 8 + 4);

    // ---- stage u[i][h] for all 100 senders (once per block) ----
    #pragma unroll
    for (int it = 0; it < 25; ++it) {
        const int r = it * 4 + w;
        const float4 xv = *reinterpret_cast<const float4*>(
            x + (((size_t)b * N_ + r) * T_ + t) * D_);
        u_lds[r][lane] = ws4.x * xv.x + ws4.y * xv.y + ws4.z * xv.z + ws4.w * xv.w;
    }

    // ---- hoist B fragments (W2^T) and b2 (once per block, registers) ----
    const int col = lane & 15;
    const int kq  = (lane >> 4) * 8;
    bf16x8 bfr[2][4];
    #pragma unroll
    for (int s = 0; s < 2; ++s)
        #pragma unroll
        for (int nt = 0; nt < 4; ++nt) {
            const float* wp = w2 + (nt * 16 + col) * H_ + s * 32 + kq;
            bfr[s][nt] = pack8(*reinterpret_cast<const float4*>(wp),
                               *reinterpret_cast<const float4*>(wp + 4));
        }
    float bb[4];
    #pragma unroll
    for (int nt = 0; nt < 4; ++nt) bb[nt] = b2[nt * 16 + col];

    __syncthreads();   // u_lds ready; everything below is wave-local

    #pragma unroll 1
    for (int rnd = 0; rnd < RPB / 4; ++rnd) {
        const int n = g * RPB + rnd * 4 + w;   // this wave's receiver
        if (n >= N_) continue;                 // wave-uniform skip

        // ---- per-wave staging: rt row, xr, v ----
        {
            const int i  = lane + (lane >= n ? 1 : 0);
            const int ed = i * (N_ - 1) + (n < i ? n : n - 1);
            rt_w[w][lane] = rel[((size_t)b * E_ + ed) * 2 + 1];
            if (lane < 48) {
                const int e2 = 64 + lane;
                float rv = 0.f;
                if (e2 < N_ - 1) {
                    const int i2  = e2 + (e2 >= n ? 1 : 0);
                    const int ed2 = i2 * (N_ - 1) + (n < i2 ? n : n - 1);
                    rv = rel[((size_t)b * E_ + ed2) * 2 + 1];
                }
                rt_w[w][e2] = rv;
            }
        }
        const float4 xr = *reinterpret_cast<const float4*>(
            x + (((size_t)b * N_ + n) * T_ + t) * D_);
        v_w[w][lane] = wr4.x * xr.x + wr4.y * xr.y + wr4.z * xr.z + wr4.w * xr.w
                       + b1[lane];

        // ---- h2 tile: M=112 (rows 99..111 masked by rt=0), N=64, K=64 ----
        f32x4 acc[7][4] = {};
        #pragma unroll
        for (int s = 0; s < 2; ++s) {
            const int kk = s * 32 + kq;
            const float4 v0 = *reinterpret_cast<const float4*>(&v_w[w][kk]);
            const float4 v1 = *reinterpret_cast<const float4*>(&v_w[w][kk + 4]);
            #pragma unroll
            for (int mf = 0; mf < 7; ++mf) {
                const int e = mf * 16 + col;
                int i = e + (e >= n ? 1 : 0);
                if (i > N_ - 1) i = N_ - 1;    // pad rows read row 99 (rt=0)
                const float* up = &u_lds[i][kk];
                const bf16x8 af = pack8_relu_add(
                    *reinterpret_cast<const float4*>(up),
                    *reinterpret_cast<const float4*>(up + 4), v0, v1);
                #pragma unroll
                for (int nt = 0; nt < 4; ++nt)
                    acc[mf][nt] = __builtin_amdgcn_mfma_f32_16x16x32_bf16(
                        af, bfr[s][nt], acc[mf][nt], 0, 0, 0);
            }
        }

        // ---- agg[g] = sum_e rt_e * relu(h2[e][g] + b2[g]) ----
        const int rq = (lane >> 4) * 2;        // f32x4 reg r -> row rq*2? no:
        // C/D layout: col = lane&15, row = (lane>>4)*4 + reg  (+16*mf)
        float aggl[4] = {0.f, 0.f, 0.f, 0.f};
        #pragma unroll
        for (int mf = 0; mf < 7; ++mf) {
            const float4 rt4 = *reinterpret_cast<const float4*>(
                &rt_w[w][mf * 16 + (lane >> 4) * 4]);
            #pragma unroll
            for (int nt = 0; nt < 4; ++nt) {
                const f32x4 a = acc[mf][nt];
                aggl[nt] += fmaxf(a[0] + bb[nt], 0.f) * rt4.x
                          + fmaxf(a[1] + bb[nt], 0.f) * rt4.y
                          + fmaxf(a[2] + bb[nt], 0.f) * rt4.z
                          + fmaxf(a[3] + bb[nt], 0.f) * rt4.w;
            }
        }
        #pragma unroll
        for (int nt = 0; nt < 4; ++nt) {
            float p = aggl[nt];
            p += __shfl_xor(p, 16, 64);
            p += __shfl_xor(p, 32, 64);
            if (lane < 16) agg_w[w][nt * 16 + col] = p;
        }

        // ---- out MLP (wave-synchronous): [x,agg] 68->64->64->4 + resid ----
        {
            float a = f1b[lane];
            const float* wr = f1w + lane * (D_ + H_);
            a = fmaf(wr[0], xr.x, a);
            a = fmaf(wr[1], xr.y, a);
            a = fmaf(wr[2], xr.z, a);
            a = fmaf(wr[3], xr.w, a);
            #pragma unroll
            for (int f = 0; f < H_; ++f)
                a = fmaf(wr[4 + f], agg_w[w][f], a);
            p1_w[w][lane] = fmaxf(a, 0.f);
        }
        {
            float a = f2b[lane];
            const float* wr = f2w + lane * H_;
            #pragma unroll
            for (int h = 0; h < H_; ++h)
                a = fmaf(wr[h], p1_w[w][h], a);
            p2_w[w][lane] = fmaxf(a, 0.f);
        }
        if (lane < D_) {
            float a = f3b[lane];
            const float* wr = f3w + lane * H_;
            #pragma unroll
            for (int h = 0; h < H_; ++h)
                a = fmaf(wr[h], p2_w[w][h], a);
            const float xv = (lane == 0) ? xr.x : (lane == 1) ? xr.y
                           : (lane == 2) ? xr.z : xr.w;
            out[(((size_t)b * N_ + n) * TP_ + t) * D_ + lane] = xv + a;
        }
    }
}

extern "C" void kernel_launch(void* const* d_in, const int* in_sizes, int n_in,
                              void* d_out, int out_size, void* d_ws, size_t ws_size,
                              hipStream_t stream) {
    const float* x   = (const float*)d_in[0];
    const float* rt  = (const float*)d_in[1];
    // d_in[2]=rel_rec, d_in[3]=rel_send: one-hot -> index arithmetic
    const float* w1  = (const float*)d_in[4] + 1 * H_ * 2 * D_;  // k=1 slice
    const float* b1  = (const float*)d_in[5] + 1 * H_;
    const float* w2  = (const float*)d_in[6] + 1 * H_ * H_;
    const float* b2  = (const float*)d_in[7] + 1 * H_;
    const float* f1w = (const float*)d_in[8];
    const float* f1b = (const float*)d_in[9];
    const float* f2w = (const float*)d_in[10];
    const float* f2b = (const float*)d_in[11];
    const float* f3w = (const float*)d_in[12];
    const float* f3b = (const float*)d_in[13];
    float* out = (float*)d_out;

    dim3 grid(B_ * TP_ * NG);
    nri_v3<<<grid, 256, 0, stream>>>(x, rt, w1, b1, w2, b2,
                                     f1w, f1b, f2w, f2b, f3w, f3b, out);
}